// Round 2
// baseline (184.662 us; speedup 1.0000x reference)
//
#include <hip/hip_runtime.h>
#include <hip/hip_bf16.h>

#define N_NODES 50000
#define N_EDGES 600000
#define IN_F 256
#define OUT_F 128
#define GEMM_BLOCKS 196    // 256 rows per block
#define NBUCK 196          // buckets = row >> 8  (50000/256 -> 196)
#define NBLK_E 128         // edge blocks for bucket histogram/scatter
#define EPB 4688           // ceil(600000/128) edges per block

typedef __bf16 bf16x8 __attribute__((ext_vector_type(8)));
typedef __bf16 bf16x2 __attribute__((ext_vector_type(2)));
typedef float  f32x4  __attribute__((ext_vector_type(4)));

__device__ __forceinline__ void async_copy16(void* lds, const void* g) {
    __builtin_amdgcn_global_load_lds(
        (const __attribute__((address_space(1))) void*)g,
        (__attribute__((address_space(3))) void*)lds, 16, 0, 0);
}

// ---------------------------------------------------------------------------
// Kernel 0: prep. wt_sw = bf16 W^T, pre-swizzled so a LINEAR 64KB LDS copy
// yields the XOR-swizzled layout the GEMM fragment reads expect:
//   LDS byte (n<<9) + (2k ^ ((n&7)<<4)) holds bf16(w[k][n]).
// (counts[] zeroing is gone: the new pipeline has no global counters.)
// ---------------------------------------------------------------------------
__global__ __launch_bounds__(256) void gcn_prep(const float* __restrict__ w,
                                                __bf16* __restrict__ wt_sw) {
    int i = blockIdx.x * 256 + threadIdx.x;       // 128 blocks -> 32768
    int n = i >> 8;                               // 0..127 (output col)
    int k = (i & 255) ^ ((n & 7) << 3);           // 0..255 (input feature)
    wt_sw[i] = (__bf16)w[k * OUT_F + n];
}

// ---------------------------------------------------------------------------
// Kernel 1 (fused): blocks [0,196) = GEMM  support = bf16(x @ W);
//                   blocks [196,324) = bucket histogram (LDS only, NO global
//                   atomics): bh[g][b] = #edges of block b with row>>8 == g.
// The 600K global atomicAdd-with-return ops (round-0/1 bottleneck: 5.8
// atomics/cycle device-wide = fabric cap, all pipes idle) are eliminated.
// ---------------------------------------------------------------------------
__global__ __launch_bounds__(512, 4) void gcn_gemm_hist(const float* __restrict__ x,
                                                        const __bf16* __restrict__ wt_sw,
                                                        __bf16* __restrict__ support,
                                                        const int* __restrict__ erows,
                                                        int* __restrict__ bh) {
    __shared__ char smem[65536];   // GEMM: W^T then C-tile; hist: 196-bin LDS histogram
    const int t = threadIdx.x;

    if (blockIdx.x >= GEMM_BLOCKS) {
        // ---------------- bucket-histogram part ----------------
        int b = blockIdx.x - GEMM_BLOCKS;         // 0..127
        int* lh = (int*)smem;
        if (t < NBUCK) lh[t] = 0;
        __syncthreads();
        int e0 = b * EPB;
        int e1 = e0 + EPB; if (e1 > N_EDGES) e1 = N_EDGES;
        for (int e = e0 + t; e < e1; e += 512)
            atomicAdd(&lh[erows[e] >> 8], 1);     // LDS atomic, per-CU
        __syncthreads();
        if (t < NBUCK) bh[t * NBLK_E + b] = lh[t];  // transposed [196][128]
        return;
    }

    // ---------------- GEMM part ----------------
    const int wave = t >> 6;                         // 0..7
    const int lane = t & 63;
    const int m    = lane & 15;
    const int quad = lane >> 4;

    // stage 64KB W^T: linear LDS dest, 8 iters x (8 waves x 64 lanes x 16B)
    {
        const char* gW = (const char*)wt_sw + wave * 1024 + lane * 16;
        char* lW = smem + wave * 1024;               // wave-uniform base
#pragma unroll
        for (int it = 0; it < 8; it++)
            async_copy16(lW + it * 8192, gW + it * 8192);
    }
    __syncthreads();   // drains vmcnt(0) for the global_load_lds queue

    const int row0 = blockIdx.x * 256 + wave * 32;
    int r0 = row0 + m;
    int r1 = row0 + 16 + m;
    const float* xp0 = x + (size_t)(r0 < N_NODES ? r0 : 0) * IN_F + quad * 8;
    const float* xp1 = x + (size_t)(r1 < N_NODES ? r1 : 0) * IN_F + quad * 8;

    f32x4 acc0[8], acc1[8];
#pragma unroll
    for (int nt = 0; nt < 8; nt++) {
        acc0[nt] = (f32x4){0.f, 0.f, 0.f, 0.f};
        acc1[nt] = (f32x4){0.f, 0.f, 0.f, 0.f};
    }

    // prime ks=0
    float4 c00 = *(const float4*)(xp0);
    float4 c01 = *(const float4*)(xp0 + 4);
    float4 c10 = *(const float4*)(xp1);
    float4 c11 = *(const float4*)(xp1 + 4);

#pragma unroll
    for (int ks = 0; ks < 8; ks++) {
        float4 n00, n01, n10, n11;
        if (ks < 7) {
            n00 = *(const float4*)(xp0 + (ks + 1) * 32);
            n01 = *(const float4*)(xp0 + (ks + 1) * 32 + 4);
            n10 = *(const float4*)(xp1 + (ks + 1) * 32);
            n11 = *(const float4*)(xp1 + (ks + 1) * 32 + 4);
        }
        bf16x8 af0 = { (__bf16)c00.x, (__bf16)c00.y, (__bf16)c00.z, (__bf16)c00.w,
                       (__bf16)c01.x, (__bf16)c01.y, (__bf16)c01.z, (__bf16)c01.w };
        bf16x8 af1 = { (__bf16)c10.x, (__bf16)c10.y, (__bf16)c10.z, (__bf16)c10.w,
                       (__bf16)c11.x, (__bf16)c11.y, (__bf16)c11.z, (__bf16)c11.w };
#pragma unroll
        for (int nt = 0; nt < 8; nt++) {
            int nrow = nt * 16 + m;
            const bf16x8 bf = *(const bf16x8*)(smem + (nrow << 9) +
                                ((ks * 64 + quad * 16) ^ ((nrow & 7) << 4)));
            acc0[nt] = __builtin_amdgcn_mfma_f32_16x16x32_bf16(af0, bf, acc0[nt], 0, 0, 0);
            acc1[nt] = __builtin_amdgcn_mfma_f32_16x16x32_bf16(af1, bf, acc1[nt], 0, 0, 0);
        }
        if (ks < 7) { c00 = n00; c01 = n01; c10 = n10; c11 = n11; }
    }

    // ---- epilogue: transpose through LDS, then full-line vector stores ----
    __syncthreads();   // all waves done reading W from smem
#pragma unroll
    for (int nt = 0; nt < 8; nt++) {
        int cb = (nt * 16 + m) * 2;                  // col byte offset
#pragma unroll
        for (int r = 0; r < 4; r++) {
            int lr0 = wave * 32 + quad * 4 + r;      // C/D layout [m89]: row=quad*4+r
            int lr1 = lr0 + 16;
            *(__bf16*)(smem + (lr0 << 8) + (cb ^ ((lr0 & 7) << 4))) = (__bf16)acc0[nt][r];
            *(__bf16*)(smem + (lr1 << 8) + (cb ^ ((lr1 & 7) << 4))) = (__bf16)acc1[nt][r];
        }
    }
    __syncthreads();
    {
        int row  = t >> 1;                           // 0..255
        int half = t & 1;
        int g = blockIdx.x * 256 + row;
        if (g < N_NODES) {
            char* dst = (char*)(support + (size_t)g * OUT_F) + half * 128;
#pragma unroll
            for (int j = 0; j < 8; j++) {
                int boff = (half * 128 + j * 16) ^ ((row & 7) << 4);
                *(bf16x8*)(dst + j * 16) = *(const bf16x8*)(smem + (row << 8) + boff);
            }
        }
    }
}

// ---------------------------------------------------------------------------
// Kernel 2: one block. From bh[196][128] compute:
//   total[g]  = bucket sizes
//   base[g][b]= absolute start of (edge-block b)'s slice of bucket g
//             = start[g] + sum_{b'<b} bh[g][b']   (start = excl scan of total)
// Wave-parallel: 16 waves, each owns buckets w, w+16, ... (coalesced loads).
// ---------------------------------------------------------------------------
__global__ __launch_bounds__(1024) void gcn_bucket_base(const int* __restrict__ bh,
                                                        int* __restrict__ base,
                                                        int* __restrict__ total) {
    __shared__ int tot[256];
    __shared__ int st[256];
    const int t = threadIdx.x;
    const int wv = t >> 6, ln = t & 63;              // 16 waves

    // phase 1: per-bucket totals
    for (int g = wv; g < NBUCK; g += 16) {
        int v = bh[g * NBLK_E + ln] + bh[g * NBLK_E + 64 + ln];
        for (int off = 32; off; off >>= 1) v += __shfl_down(v, off, 64);
        if (ln == 0) tot[g] = v;
    }
    __syncthreads();

    // phase 2: inclusive scan over 196 totals (classic LDS scan, 256-wide)
    if (t < 256) st[t] = (t < NBUCK) ? tot[t] : 0;
    __syncthreads();
    for (int off = 1; off < 256; off <<= 1) {
        int x = 0;
        if (t < 256 && t >= off) x = st[t - off];
        __syncthreads();
        if (t < 256) st[t] += x;
        __syncthreads();
    }
    if (t < NBUCK) total[t] = tot[t];
    __syncthreads();

    // phase 3: per-bucket exclusive scan across the 128 edge-blocks
    for (int g = wv; g < NBUCK; g += 16) {
        int start = st[g] - tot[g];                  // exclusive bucket start
        int v0 = bh[g * NBLK_E + ln];
        int v1 = bh[g * NBLK_E + 64 + ln];
        int s0 = v0;
        for (int off = 1; off < 64; off <<= 1) {
            int u = __shfl_up(s0, off, 64);
            if (ln >= off) s0 += u;
        }
        int t0 = __shfl(s0, 63, 64);
        int s1 = v1;
        for (int off = 1; off < 64; off <<= 1) {
            int u = __shfl_up(s1, off, 64);
            if (ln >= off) s1 += u;
        }
        base[g * NBLK_E + ln]      = start + s0 - v0;
        base[g * NBLK_E + 64 + ln] = start + t0 + s1 - v1;
    }
}

// ---------------------------------------------------------------------------
// Kernel 3: scatter edges to bucket-major order. Rank within (block,bucket)
// via LDS atomic returns; cnt[] pre-initialized with the absolute base so the
// returned value IS the destination index. Packed 8B: (localrow<<16 | col, val).
// ---------------------------------------------------------------------------
__global__ __launch_bounds__(512) void gcn_bucket_scatter(const int* __restrict__ erows,
                                                          const int* __restrict__ ecols,
                                                          const float* __restrict__ evals,
                                                          const int* __restrict__ base,
                                                          int2* __restrict__ bucketed) {
    __shared__ int cnt[NBUCK];
    const int b = blockIdx.x;
    const int t = threadIdx.x;
    if (t < NBUCK) cnt[t] = base[t * NBLK_E + b];
    __syncthreads();
    int e0 = b * EPB;
    int e1 = e0 + EPB; if (e1 > N_EDGES) e1 = N_EDGES;
    for (int e = e0 + t; e < e1; e += 512) {
        int r = erows[e];
        int g = r >> 8;
        int pos = atomicAdd(&cnt[g], 1);             // LDS atomic return
        bucketed[pos] = make_int2(((r & 255) << 16) | ecols[e],
                                  __float_as_int(evals[e]));
    }
}

// ---------------------------------------------------------------------------
// Kernel 4: per-bucket fine rank. One block per bucket (256 rows): LDS 256-bin
// count -> LDS scan -> write CSR row_start[] directly -> LDS-atomic scatter to
// the final row-sorted sorted_cv. Replaces scan1/scan2/old-scatter and removes
// the per-block partials scan from the aggregate kernel.
// ---------------------------------------------------------------------------
__global__ __launch_bounds__(256) void gcn_bucket_rank(const int2* __restrict__ bucketed,
                                                       const int* __restrict__ base,
                                                       const int* __restrict__ total,
                                                       int2* __restrict__ sorted_cv,
                                                       int* __restrict__ row_start) {
    __shared__ int lh[256];
    __shared__ int s[256];
    __shared__ int run[256];
    const int g = blockIdx.x;
    const int t = threadIdx.x;
    const int s0 = base[g * NBLK_E];                 // bucket start (b=0 prefix = 0)
    const int ne = total[g];

    lh[t] = 0;
    __syncthreads();
    for (int i = t; i < ne; i += 256)
        atomicAdd(&lh[bucketed[s0 + i].x >> 16], 1);
    __syncthreads();

    int v = lh[t];
    s[t] = v;
    __syncthreads();
#pragma unroll
    for (int off = 1; off < 256; off <<= 1) {
        int x = (t >= off) ? s[t - off] : 0;
        __syncthreads();
        s[t] += x;
        __syncthreads();
    }
    int excl = s[t] - v;                             // exclusive within bucket

    int gr = g * 256 + t;
    if (gr < N_NODES) row_start[gr] = s0 + excl;
    if (gr == N_NODES) row_start[gr] = N_EDGES;      // CSR sentinel (block 195, t=80)
    run[t] = s0 + excl;
    __syncthreads();

    for (int i = t; i < ne; i += 256) {
        int2 cv = bucketed[s0 + i];
        int lr = cv.x >> 16;
        int pos = atomicAdd(&run[lr], 1);            // LDS atomic return
        sorted_cv[pos] = make_int2(cv.x & 0xFFFF, cv.y);
    }
}

// ---------------------------------------------------------------------------
// Kernel 5: aggregate. One wave per node; bf16x2/lane covers 128 cols.
// beg/end straight from CSR row_start. Unroll-8 (MLP=8). No LDS.
// out[n] = bias + sum_{e in row n} val_e * support[col_e]
// ---------------------------------------------------------------------------
__global__ __launch_bounds__(512) void gcn_aggregate_csr(const __bf16* __restrict__ support,
                                                         const int2* __restrict__ sorted_cv,
                                                         const int* __restrict__ row_start,
                                                         const float* __restrict__ bias,
                                                         float* __restrict__ out) {
    const int t = threadIdx.x;
    const int node = (blockIdx.x * 512 + t) >> 6;
    const int lane = t & 63;
    if (node >= N_NODES) return;

    const int beg = row_start[node];
    const int end = row_start[node + 1];

    float2 accA = *(const float2*)&bias[lane * 2];
    float2 accB = make_float2(0.f, 0.f);
    const __bf16* sp = support + lane * 2;

    int i = beg;
    for (; i + 7 < end; i += 8) {
        int2 cv0 = sorted_cv[i];
        int2 cv1 = sorted_cv[i + 1];
        int2 cv2 = sorted_cv[i + 2];
        int2 cv3 = sorted_cv[i + 3];
        int2 cv4 = sorted_cv[i + 4];
        int2 cv5 = sorted_cv[i + 5];
        int2 cv6 = sorted_cv[i + 6];
        int2 cv7 = sorted_cv[i + 7];
        bf16x2 s0 = *(const bf16x2*)(sp + (size_t)cv0.x * OUT_F);
        bf16x2 s1 = *(const bf16x2*)(sp + (size_t)cv1.x * OUT_F);
        bf16x2 s2 = *(const bf16x2*)(sp + (size_t)cv2.x * OUT_F);
        bf16x2 s3 = *(const bf16x2*)(sp + (size_t)cv3.x * OUT_F);
        bf16x2 s4 = *(const bf16x2*)(sp + (size_t)cv4.x * OUT_F);
        bf16x2 s5 = *(const bf16x2*)(sp + (size_t)cv5.x * OUT_F);
        bf16x2 s6 = *(const bf16x2*)(sp + (size_t)cv6.x * OUT_F);
        bf16x2 s7 = *(const bf16x2*)(sp + (size_t)cv7.x * OUT_F);
        accA.x += __int_as_float(cv0.y) * (float)s0.x + __int_as_float(cv1.y) * (float)s1.x;
        accA.y += __int_as_float(cv0.y) * (float)s0.y + __int_as_float(cv1.y) * (float)s1.y;
        accB.x += __int_as_float(cv2.y) * (float)s2.x + __int_as_float(cv3.y) * (float)s3.x;
        accB.y += __int_as_float(cv2.y) * (float)s2.y + __int_as_float(cv3.y) * (float)s3.y;
        accA.x += __int_as_float(cv4.y) * (float)s4.x + __int_as_float(cv5.y) * (float)s5.x;
        accA.y += __int_as_float(cv4.y) * (float)s4.y + __int_as_float(cv5.y) * (float)s5.y;
        accB.x += __int_as_float(cv6.y) * (float)s6.x + __int_as_float(cv7.y) * (float)s7.x;
        accB.y += __int_as_float(cv6.y) * (float)s6.y + __int_as_float(cv7.y) * (float)s7.y;
    }
    for (; i + 3 < end; i += 4) {
        int2 cv0 = sorted_cv[i];
        int2 cv1 = sorted_cv[i + 1];
        int2 cv2 = sorted_cv[i + 2];
        int2 cv3 = sorted_cv[i + 3];
        bf16x2 s0 = *(const bf16x2*)(sp + (size_t)cv0.x * OUT_F);
        bf16x2 s1 = *(const bf16x2*)(sp + (size_t)cv1.x * OUT_F);
        bf16x2 s2 = *(const bf16x2*)(sp + (size_t)cv2.x * OUT_F);
        bf16x2 s3 = *(const bf16x2*)(sp + (size_t)cv3.x * OUT_F);
        accA.x += __int_as_float(cv0.y) * (float)s0.x + __int_as_float(cv1.y) * (float)s1.x;
        accA.y += __int_as_float(cv0.y) * (float)s0.y + __int_as_float(cv1.y) * (float)s1.y;
        accB.x += __int_as_float(cv2.y) * (float)s2.x + __int_as_float(cv3.y) * (float)s3.x;
        accB.y += __int_as_float(cv2.y) * (float)s2.y + __int_as_float(cv3.y) * (float)s3.y;
    }
    for (; i < end; i++) {
        int2 cv = sorted_cv[i];
        float vv = __int_as_float(cv.y);
        bf16x2 sv = *(const bf16x2*)(sp + (size_t)cv.x * OUT_F);
        accA.x += vv * (float)sv.x;
        accA.y += vv * (float)sv.y;
    }
    accA.x += accB.x;
    accA.y += accB.y;

    *(float2*)&out[(size_t)node * OUT_F + lane * 2] = accA;
}

// ---------------------------------------------------------------------------
static inline size_t align_up(size_t v, size_t a) { return (v + a - 1) & ~(a - 1); }

extern "C" void kernel_launch(void* const* d_in, const int* in_sizes, int n_in,
                              void* d_out, int out_size, void* d_ws, size_t ws_size,
                              hipStream_t stream) {
    const float* x     = (const float*)d_in[0];   // [50000, 256]
    const int*   erows = (const int*)d_in[1];     // [600000]
    const int*   ecols = (const int*)d_in[2];     // [600000]
    const float* evals = (const float*)d_in[3];   // [600000]
    const float* w     = (const float*)d_in[4];   // [256, 128]
    const float* bias  = (const float*)d_in[5];   // [128]
    float* out = (float*)d_out;                   // [50000, 128]

    // workspace layout (all regions 64B-aligned; ~23 MB total)
    size_t off = 0;
    __bf16* support   = (__bf16*)((char*)d_ws + off);
    off = align_up(off + (size_t)N_NODES * OUT_F * 2, 64);
    __bf16* wt_sw     = (__bf16*)((char*)d_ws + off);
    off = align_up(off + (size_t)IN_F * OUT_F * 2, 64);
    int*    bh        = (int*)((char*)d_ws + off);        // [196][128]
    off = align_up(off + (size_t)NBUCK * NBLK_E * 4, 64);
    int*    base      = (int*)((char*)d_ws + off);        // [196][128]
    off = align_up(off + (size_t)NBUCK * NBLK_E * 4, 64);
    int*    total     = (int*)((char*)d_ws + off);        // [196]
    off = align_up(off + 256 * 4, 64);
    int*    row_start = (int*)((char*)d_ws + off);        // [50001] CSR
    off = align_up(off + (size_t)(N_NODES + 1) * 4, 64);
    int2*   bucketed  = (int2*)((char*)d_ws + off);       // [600000] bucket-major
    off = align_up(off + (size_t)N_EDGES * 8, 64);
    int2*   sorted_cv = (int2*)((char*)d_ws + off);       // [600000] row-sorted

    // 0) build swizzled bf16 W^T (no global counters to zero anymore)
    gcn_prep<<<(IN_F * OUT_F) / 256, 256, 0, stream>>>(w, wt_sw);

    // 1) fused GEMM + bucket histogram (zero global atomics)
    gcn_gemm_hist<<<GEMM_BLOCKS + NBLK_E, 512, 0, stream>>>(
        x, wt_sw, support, erows, bh);

    // 2) bases: one block, wave-parallel scans
    gcn_bucket_base<<<1, 1024, 0, stream>>>(bh, base, total);

    // 3) scatter to bucket-major (LDS atomic ranks)
    gcn_bucket_scatter<<<NBLK_E, 512, 0, stream>>>(erows, ecols, evals, base, bucketed);

    // 4) per-bucket fine rank -> CSR row_start + row-sorted edges
    gcn_bucket_rank<<<NBUCK, 256, 0, stream>>>(bucketed, base, total, sorted_cv, row_start);

    // 5) aggregate + bias (one wave per node)
    gcn_aggregate_csr<<<(N_NODES * 64 + 511) / 512, 512, 0, stream>>>(
        support, sorted_cv, row_start, bias, out);
}